// Round 10
// baseline (278.257 us; speedup 1.0000x reference)
//
#include <hip/hip_runtime.h>
#include <math.h>

#define N_NODES 100000
#define N_EDGES 6400000
#define F_IN 128
#define F_OUT 16
#define NB 391                 // ceil(100000/256) buckets of 256 target nodes
#define NBLK 1600              // chunks
#define EPB 4000               // edges per chunk: 1600 * 4000 = 6.4M exactly
#define LOCW 392               // loc row width
#define KPB 4                  // scatter blocks per bucket (1564 blocks)
#define ACCN (NB * 256 * F_OUT)
#define QSCALE 1024.0f         // 2^10 fixed-point scale for the int16 gather table
#define QINV   (1.0f / 1024.0f)
#define FIN_GRID 640
#define SACCW 17               // sacc node stride: kills parity bank conflicts

// -------- 1. per-chunk per-bucket counts; also zeros the deg array --------
__global__ void __launch_bounds__(256) count_kernel(const int* __restrict__ col,
                                                    int* __restrict__ loc,
                                                    int* __restrict__ deg) {
    __shared__ int hist[NB];
    const int t = threadIdx.x, k = blockIdx.x;
    const int z0 = k * 63;                       // 1600*63 >= 100000
    for (int j = t; j < 63; j += 256)
        if (z0 + j < N_NODES) deg[z0 + j] = 0;
    for (int i = t; i < NB; i += 256) hist[i] = 0;
    __syncthreads();
    const int e0 = k * EPB;
    for (int i = t; i < EPB; i += 256) atomicAdd(&hist[col[e0 + i] >> 8], 1);
    __syncthreads();
    for (int b = t; b < NB; b += 256) loc[k * LOCW + b] = hist[b];
}

// -------- 2. per-bucket exclusive prefix over chunks + fused bucket-total scan
//            (last block performs the 391-wide scan -> boffs) --------
__global__ void __launch_bounds__(256) desta_kernel(const int* __restrict__ loc,
        int* __restrict__ destT, int* __restrict__ total, int* __restrict__ boffs,
        int* __restrict__ done2) {
    __shared__ int tsum[256];
    __shared__ int lastflag;
    const int t = threadIdx.x, b = blockIdx.x;
    int v[7]; int s = 0;
    #pragma unroll
    for (int j = 0; j < 7; j++) {
        int k = t * 7 + j;
        v[j] = (k < NBLK) ? loc[k * LOCW + b] : 0;
        s += v[j];
    }
    tsum[t] = s;
    __syncthreads();
    for (int off = 1; off < 256; off <<= 1) {
        int a = (t >= off) ? tsum[t - off] : 0;
        __syncthreads();
        tsum[t] += a;
        __syncthreads();
    }
    int run = tsum[t] - s;   // exclusive prefix
    #pragma unroll
    for (int j = 0; j < 7; j++) {
        int k = t * 7 + j;
        if (k < NBLK) destT[(size_t)b * NBLK + k] = run;
        run += v[j];
    }
    if (t == 255) atomicExch(&total[b], tsum[255]);  // device-coherent publish
    if (t == 0) {
        __threadfence();
        lastflag = (atomicAdd(done2, 1) == (int)gridDim.x - 1);
    }
    __syncthreads();
    if (!lastflag) return;
    // last block: exclusive scan of 391 totals -> boffs (2 elems/thread)
    __shared__ int scanb[512];
    int v0 = (t < NB) ? atomicAdd(&total[t], 0) : 0;
    int v1 = (t + 256 < NB) ? atomicAdd(&total[t + 256], 0) : 0;
    scanb[t] = v0; scanb[t + 256] = v1;
    __syncthreads();
    for (int off = 1; off < 512; off <<= 1) {
        int a  = (t >= off) ? scanb[t - off] : 0;
        int a2 = scanb[t + 256 - off];
        __syncthreads();
        scanb[t] += a; scanb[t + 256] += a2;
        __syncthreads();
    }
    if (t < NB) boffs[t] = scanb[t] - v0;
    if (t + 256 < NB) boffs[t + 256] = scanb[t + 256] - v1;
    if (t == 0) boffs[NB] = N_EDGES;
}

// -------- 3. place: LDS counting-sort each chunk, flush segments DIRECTLY to
//            bucket-contiguous global positions. --------
__global__ void __launch_bounds__(256) place_kernel(const int* __restrict__ row,
        const int* __restrict__ col, const int* __restrict__ destT,
        const int* __restrict__ boffs, unsigned int* __restrict__ packed) {
    __shared__ int hist[NB];
    __shared__ int scanb[512];
    __shared__ int base[NB];
    __shared__ int gadj[NB];
    __shared__ unsigned int tile[EPB];      // 16 KB
    __shared__ unsigned short tileb[EPB];   // 8 KB (bucket id per slot)
    const int t = threadIdx.x, k = blockIdx.x;
    const int e0 = k * EPB;
    int myc[16], myr[16];
    #pragma unroll
    for (int j = 0; j < 16; j++) {
        int idx = t + j * 256;
        if (idx < EPB) { myc[j] = col[e0 + idx]; myr[j] = row[e0 + idx]; }
        else { myc[j] = -1; myr[j] = 0; }
    }
    for (int i = t; i < NB; i += 256) hist[i] = 0;
    __syncthreads();
    #pragma unroll
    for (int j = 0; j < 16; j++)
        if (myc[j] >= 0) atomicAdd(&hist[myc[j] >> 8], 1);
    __syncthreads();
    scanb[t] = (t < NB) ? hist[t] : 0;
    scanb[t + 256] = (t + 256 < NB) ? hist[t + 256] : 0;
    __syncthreads();
    for (int off = 1; off < 512; off <<= 1) {
        int a  = (t >= off) ? scanb[t - off] : 0;
        int a2 = scanb[t + 256 - off];
        __syncthreads();
        scanb[t] += a; scanb[t + 256] += a2;
        __syncthreads();
    }
    if (t < NB) base[t] = scanb[t] - hist[t];
    if (t + 256 < NB) base[t + 256] = scanb[t + 256] - hist[t + 256];
    __syncthreads();
    for (int bb = t; bb < NB; bb += 256) {
        gadj[bb] = boffs[bb] + destT[(size_t)bb * NBLK + k] - base[bb];
        hist[bb] = 0;   // reuse as cursor
    }
    __syncthreads();
    #pragma unroll
    for (int j = 0; j < 16; j++) {
        if (myc[j] >= 0) {
            int bb = myc[j] >> 8;
            int pos = base[bb] + atomicAdd(&hist[bb], 1);     // native ds_add_rtn
            tile[pos] = ((unsigned)myr[j] << 8) | (unsigned)(myc[j] & 255);
            tileb[pos] = (unsigned short)bb;
        }
    }
    __syncthreads();
    for (int i = t; i < EPB; i += 256)
        packed[gadj[tileb[i]] + i] = tile[i];   // segment-contiguous global writes
}

// -------- 4. per-bucket degree, 4 slices per bucket, global int merge --------
__global__ void __launch_bounds__(256) deg_kernel(const unsigned int* __restrict__ packed,
        const int* __restrict__ boffs, int* __restrict__ deg) {
    __shared__ int dh[256];
    const int t = threadIdx.x;
    dh[t] = 0;
    __syncthreads();
    const int b = blockIdx.x, part = blockIdx.y;
    const int s = boffs[b], e = boffs[b + 1];
    const int chunk = (e - s + 3) >> 2;
    const int cs = s + part * chunk;
    const int ce = min(cs + chunk, e);
    for (int i = cs + t; i < ce; i += 256)
        atomicAdd(&dh[packed[i] & 255u], 1);
    __syncthreads();
    const int node = (b << 8) + t;
    if (node < N_NODES && dh[t]) atomicAdd(&deg[node], dh[t]);
}

// -------- 5. gq[n,f] = int16( rsqrt(deg+1) * (x@W)[n,f] * 2^10 ) --------
// W staged TRANSPOSED (Wt[f][k], stride 132) -> both operands read as float4.
__global__ void __launch_bounds__(256) gemm_kernel(const float* __restrict__ x,
        const float* __restrict__ W, const int* __restrict__ deg,
        short* __restrict__ gq) {
    __shared__ float Wt[16 * 132];            // 8.4 KB
    __shared__ float xs[16 * 132];            // stride 132: float4-aligned, conflict-free
    const int tid = threadIdx.x;
    const int n0 = blockIdx.x * 16;
    for (int i = tid; i < 2048; i += 256) {   // W[k][f] -> Wt[f][k]
        int k = i >> 4, f2 = i & 15;
        Wt[f2 * 132 + k] = W[i];
    }
    const float4* x4 = (const float4*)(x + (size_t)n0 * F_IN);   // 16 rows x 32 float4
    for (int i = tid; i < 512; i += 256) {
        int n = i >> 5, j = i & 31;
        *(float4*)(xs + n * 132 + j * 4) = x4[i];
    }
    __syncthreads();
    const int node = tid >> 4, f = tid & 15;
    const float4* xr4 = (const float4*)(xs + node * 132);
    const float4* wr4 = (const float4*)(Wt + f * 132);
    float acc = 0.f;
    #pragma unroll 8
    for (int k = 0; k < 32; k++) {
        float4 a = xr4[k], w = wr4[k];
        acc += a.x * w.x + a.y * w.y + a.z * w.z + a.w * w.w;
    }
    const float dinvn = rsqrtf((float)deg[n0 + node] + 1.0f);    // +1 self loop
    float v = acc * dinvn * QSCALE;
    v = fminf(fmaxf(v, -32000.f), 32000.f);
    gq[n0 * 16 + tid] = (short)__float2int_rn(v);
}

// -------- 6. dense scatter: each 16-lane group loads 4 consecutive edges as
//            ONE uint4 (broadcast), gathers int16, native ds_add into
//            stride-17 sacc (bank-conflict-free). KPB=4 slices. --------
__global__ void __launch_bounds__(256) scatter_kernel(
        const unsigned int* __restrict__ packed, const int* __restrict__ boffs,
        const short* __restrict__ gq, int* __restrict__ accp) {
    __shared__ int sacc[256 * SACCW];   // 17 KB
    const int t = threadIdx.x;
    for (int i = t; i < 256 * SACCW; i += 256) sacc[i] = 0;
    __syncthreads();
    const int b = blockIdx.x, part = blockIdx.y;
    const int s = boffs[b], e = boffs[b + 1];
    const int chunk = (e - s + KPB - 1) / KPB;
    const int cs = s + part * chunk;
    const int ce = min(cs + chunk, e);
    const int f = t & 15, eg = t >> 4;    // 16 groups x 4 consecutive edges
    const int cs_al = (cs + 3) & ~3;      // uint4 alignment
    if (eg == 0) {                        // prologue (<=3 edges)
        int pe = min(cs_al, ce);
        for (int j = cs; j < pe; j++) {
            unsigned p0 = packed[j];
            atomicAdd(&sacc[(p0 & 255u) * SACCW + f], (int)gq[(p0 >> 8) * 16 + f]);
        }
    }
    int i = cs_al + eg * 4;
    for (; i + 3 < ce; i += 64) {
        uint4 pk = *(const uint4*)(packed + i);   // one 16B load per 4 edges
        int v0 = gq[(pk.x >> 8) * 16 + f];
        int v1 = gq[(pk.y >> 8) * 16 + f];
        int v2 = gq[(pk.z >> 8) * 16 + f];
        int v3 = gq[(pk.w >> 8) * 16 + f];
        atomicAdd(&sacc[(pk.x & 255u) * SACCW + f], v0);
        atomicAdd(&sacc[(pk.y & 255u) * SACCW + f], v1);
        atomicAdd(&sacc[(pk.z & 255u) * SACCW + f], v2);
        atomicAdd(&sacc[(pk.w & 255u) * SACCW + f], v3);
    }
    const int jend = min(ce, i + 4);      // this group's clipped last quad
    for (int j = i; j < jend; j++) {
        unsigned p0 = packed[j];
        atomicAdd(&sacc[(p0 & 255u) * SACCW + f], (int)gq[(p0 >> 8) * 16 + f]);
    }
    __syncthreads();
    const int nbase = b << 8;
    int* dst = accp + (size_t)part * ACCN + ((size_t)nbase << 4);
    for (int j = t; j < 256 * F_OUT; j += 256)
        if (nbase + (j >> 4) < N_NODES) dst[j] = sacc[(j >> 4) * SACCW + (j & 15)];
}

// -------- 7. out_n = tanh(dinv[n]*(acc+g) + b); mean; fused final output --------
__global__ void __launch_bounds__(256) finalize_kernel(const int* __restrict__ accp,
        const short* __restrict__ gq, const int* __restrict__ deg,
        const float* __restrict__ b, double* __restrict__ dsum,
        int* __restrict__ done, float* __restrict__ out) {
    __shared__ float s[4][16];
    __shared__ int lastflag;
    const int tid = threadIdx.x;
    const int f = tid & 15;
    const float bf = b[f];
    float local = 0.f;
    for (int i = blockIdx.x * blockDim.x + tid; i < N_NODES * F_OUT;
         i += gridDim.x * blockDim.x) {
        const int n = i >> 4;
        int ai = accp[i] + accp[ACCN + i] + accp[2 * ACCN + i] + accp[3 * ACCN + i]
               + (int)gq[i];
        float dinvn = rsqrtf((float)deg[n] + 1.0f);
        local += tanhf(dinvn * ((float)ai * QINV) + bf);
    }
    local += __shfl_down(local, 32);
    local += __shfl_down(local, 16);
    const int lane = tid & 63, wave = tid >> 6;
    if (lane < 16) s[wave][lane] = local;
    __syncthreads();
    if (tid < 16) {
        float v = s[0][tid] + s[1][tid] + s[2][tid] + s[3][tid];
        atomicAdd(&dsum[tid], (double)v);
    }
    if (tid == 0) {
        __threadfence();
        lastflag = (atomicAdd(done, 1) == (int)gridDim.x - 1);
    }
    __syncthreads();
    if (lastflag && tid < 16) {
        double v = atomicAdd(&dsum[tid], 0.0);   // coherent read
        out[tid] = (float)(v * (1.0 / (double)N_NODES));
    }
}

extern "C" void kernel_launch(void* const* d_in, const int* in_sizes, int n_in,
                              void* d_out, int out_size, void* d_ws, size_t ws_size,
                              hipStream_t stream) {
    const float* x  = (const float*)d_in[0];
    const int*   ei = (const int*)d_in[1];
    const float* W  = (const float*)d_in[2];
    const float* b  = (const float*)d_in[3];
    float* out = (float*)d_out;

    const int* row = ei;             // edge_index[0] = source
    const int* col = ei + N_EDGES;   // edge_index[1] = target

    // workspace layout (~54.9 MB); loc+destT overlaid with accp (disjoint lifetimes):
    char* p = (char*)d_ws;
    double*       dsum   = (double*)p;        p += 16 * 8;
    int*          done   = (int*)p;           p += 16;   // [0]=finalize, [1]=desta
    int*          total  = (int*)p;           p += 1568;
    int*          boffs  = (int*)p;           p += (NB + 1) * 4;    // 1568
    int*          deg    = (int*)p;           p += (size_t)N_NODES * 4;        // 0.4 MB
    short*        gq     = (short*)p;         p += (size_t)N_NODES * F_OUT * 2; // 3.2 MB
    unsigned int* packed = (unsigned int*)p;  p += (size_t)N_EDGES * 4;        // 25.6 MB
    char*         shared = p;                 // max(loc+destT, accp) = 25.6 MB
    int*          loc    = (int*)shared;                               // 2.5 MB
    int*          destT  = (int*)(shared + (size_t)NBLK * LOCW * 4);   // 2.5 MB
    int*          accp   = (int*)shared;                               // KPB*ACCN i32

    hipMemsetAsync(dsum, 0, 16 * 8 + 16, stream);   // dsum + done[0..3]

    count_kernel   <<<NBLK, 256, 0, stream>>>(col, loc, deg);
    desta_kernel   <<<NB, 256, 0, stream>>>(loc, destT, total, boffs, done + 1);
    place_kernel   <<<NBLK, 256, 0, stream>>>(row, col, destT, boffs, packed);
    deg_kernel     <<<dim3(NB, 4), 256, 0, stream>>>(packed, boffs, deg);
    gemm_kernel    <<<N_NODES / 16, 256, 0, stream>>>(x, W, deg, gq);
    scatter_kernel <<<dim3(NB, KPB), 256, 0, stream>>>(packed, boffs, gq, accp);
    finalize_kernel<<<FIN_GRID, 256, 0, stream>>>(accp, gq, deg, b, dsum, done, out);
}